// Round 8
// baseline (93.798 us; speedup 1.0000x reference)
//
#include <hip/hip_runtime.h>
#include <hip/hip_bf16.h>

typedef _Float16 f16;
typedef f16 f16x4 __attribute__((ext_vector_type(4)));
typedef f16 f16x8 __attribute__((ext_vector_type(8)));
typedef float f32x4 __attribute__((ext_vector_type(4)));

#define DIM   768
#define NP    196
#define BATCH 64
#define MROWS (BATCH * NP)        // 12544
#define NCOLS (3 * DIM)           // 2304
#define GRIDF 14.0f

// ---------------- Kernel 1: f32 -> f16 conversion of x and [Wq;Wk;Wv] + bias array ----------------
#define NX4   (MROWS * DIM / 4)   // 2,408,448
#define NW4   (DIM * DIM / 4)     // 147,456 per W
#define NB4   (NCOLS / 4)         // 576
#define NCVTA (NX4 + 3 * NW4 + NB4)

__global__ __launch_bounds__(256) void convert_inputs(
    const float* __restrict__ x,
    const float* __restrict__ Wq, const float* __restrict__ Wk, const float* __restrict__ Wv,
    const float* __restrict__ bq, const float* __restrict__ bk, const float* __restrict__ bv,
    f16* __restrict__ x_h, f16* __restrict__ W_h, float* __restrict__ bias_all) {
  int i = blockIdx.x * 256 + threadIdx.x;
  if (i >= NCVTA) return;
  if (i < NX4 + 3 * NW4) {
    const float* src;
    f16* dst;
    int j;
    if (i < NX4) { src = x; dst = x_h; j = i; }
    else {
      j = i - NX4;
      if (j < NW4)          { src = Wq; dst = W_h; }
      else if (j < 2 * NW4) { src = Wk; dst = W_h + DIM * DIM;     j -= NW4; }
      else                  { src = Wv; dst = W_h + 2 * DIM * DIM; j -= 2 * NW4; }
    }
    float4 v = ((const float4*)src)[j];
    f16x4 h;
    h[0] = (f16)v.x; h[1] = (f16)v.y; h[2] = (f16)v.z; h[3] = (f16)v.w;
    ((f16x4*)dst)[j] = h;
  } else {
    int j = i - (NX4 + 3 * NW4);   // 0..575
    float4 v = (j < 192) ? ((const float4*)bq)[j]
             : (j < 384) ? ((const float4*)bk)[j - 192]
                         : ((const float4*)bv)[j - 384];
    ((float4*)bias_all)[j] = v;
  }
}

// ---------------- Kernel 2: qkv = x_h @ W_h^T + bias (128x128, BK=32, 4 waves, 3-4 blocks/CU) -----
// A: (12544 x 768) f16 rm. W: (2304 x 768) f16 rm (B^T). BM=BN=128, BK=32,
// 4 waves (2M x 2N), wave tile 64x64 (acc = 64 regs). LDS 32 KB double-buffered.
// Occupancy experiment: small acc + small LDS -> 3-4 co-resident blocks/CU; cross-block
// TLP covers ds-read latency and vmcnt waits (m97 mechanism). 2 phases/tile:
//   ph1: all 8 fragment ds_reads (both bufs fully consumed here); BAR; LGKM0; 8 MFMA; BAR
//   ph2: stage tile t+2 into current buf (safe: ph1 barrier proved buf consumed);
//        8 MFMA; vmcnt(4) drains tile t+1; BAR
// Swizzle (BK=32, 4 slots/row): slot ^= (row&3)^((row>>2)&3) -> max 2 lanes/bank (free).
// Source pre-swizzled, LDS dest linear (rule #21).

#define BM 128
#define BN 128
#define BK 32
#define NT (DIM / BK)   // 24

__device__ __forceinline__ void gl_lds16(const f16* g, f16* l) {
  __builtin_amdgcn_global_load_lds(
      (const __attribute__((address_space(1))) void*)g,
      (__attribute__((address_space(3))) void*)l, 16, 0, 0);
}

#define MFMA16(acc_, av, bv) acc_ = __builtin_amdgcn_mfma_f32_16x16x32_f16(av, bv, acc_, 0, 0, 0)
#define BAR    __builtin_amdgcn_s_barrier()
#define LGKM0  asm volatile("s_waitcnt lgkmcnt(0)" ::: "memory")
#define VMCNT4 asm volatile("s_waitcnt vmcnt(4)" ::: "memory")
#define VMCNT0 asm volatile("s_waitcnt vmcnt(0)" ::: "memory")

#define sAoff(buf) ((buf) * (BM * BK))
#define sBoff(buf) (2 * BM * BK + (buf) * (BN * BK))

__global__ __launch_bounds__(256, 4) void gemm_qkv(
    const f16* __restrict__ A, const f16* __restrict__ W,
    const float* __restrict__ bias_all, f16* __restrict__ C) {
  __shared__ __align__(16) f16 lds[4 * BM * BK];   // 32768 B

  const int t    = threadIdx.x;
  const int lane = t & 63;
  const int wid  = t >> 6;
  const int wr   = wid >> 1;       // 0..1 (M)
  const int wc   = wid & 1;        // 0..1 (N)

  // Bijective XCD swizzle (m204) over 1764 blocks; logical: n fastest (18 N-blocks)
  const int nwg = 98 * 18, qq = nwg / 8, rr = nwg % 8;   // q=220, r=4
  const int xcd = blockIdx.x & 7, seq = blockIdx.x >> 3;
  const int logical = (xcd < rr ? xcd * (qq + 1) : rr * (qq + 1) + (xcd - rr) * qq) + seq;
  const int bm0 = (logical / 18) * BM;
  const int bn0 = (logical % 18) * BN;

  // Staging: thread covers (row = t>>2, slot = t&3), 16B each; 256 thr = 64 rows/issue.
  // Source column pre-swizzled, LDS dest linear (byte off = 16*t within each 64-row chunk).
  const int srow  = t >> 2;                                  // 0..63
  const int sslot = t & 3;
  const int sswz  = (srow & 3) ^ ((srow >> 2) & 3);          // same for row srow+64
  const int gcol  = 8 * (sslot ^ sswz);                      // swizzled source col (f16)
  const int lds_off = srow * BK + sslot * 8;                 // linear dest (f16) = 8*t
  const f16* gAr = A + (size_t)(bm0 + srow) * DIM + gcol;
  const f16* gBr = W + (size_t)(bn0 + srow) * DIM + gcol;

#define STAGE_A(kt) do {                                             \
    const f16* _g = gAr + (kt) * BK;                                 \
    f16* _l = &lds[sAoff((kt) & 1) + lds_off];                       \
    gl_lds16(_g, _l);                                                \
    gl_lds16(_g + (size_t)64 * DIM, _l + 64 * BK);                   \
  } while (0)

#define STAGE_B(kt) do {                                             \
    const f16* _g = gBr + (kt) * BK;                                 \
    f16* _l = &lds[sBoff((kt) & 1) + lds_off];                       \
    gl_lds16(_g, _l);                                                \
    gl_lds16(_g + (size_t)64 * DIM, _l + 64 * BK);                   \
  } while (0)

  // Fragment-read coords: row = (wave base) + sub*16 + rl; slot = kg ^ rowswz.
  // rowswz = (row&3)^((row>>2)&3) = (rl&3)^((rl>>2)&3) (base terms vanish mod 4).
  const int rl = lane & 15;
  const int kg = lane >> 4;                                  // 0..3
  const int lswz = (rl & 3) ^ ((rl >> 2) & 3);
  const int slotF = ((kg ^ lswz) & 3) * 8;                   // f16 units
  const int aBase = (wr * 64 + rl) * BK + slotF;
  const int bBase = (wc * 64 + rl) * BK + slotF;

  f32x4 acc[4][4] = {};
  f16x8 afr[4], bfr[4];

#define LDB(buf) do {                                                            \
    _Pragma("unroll") for (int ni = 0; ni < 4; ++ni)                             \
      bfr[ni] = *(const f16x8*)&lds[sBoff(buf) + bBase + ni * 16 * BK];          \
    } while (0)

#define LDA(buf) do {                                                            \
    _Pragma("unroll") for (int mi = 0; mi < 4; ++mi)                             \
      afr[mi] = *(const f16x8*)&lds[sAoff(buf) + aBase + mi * 16 * BK];          \
    } while (0)

  // SWAPPED operand order: mfma(bfr, afr) -> m = lane&15 (A row), n = 4*kg + reg (B row)
#define MMA2(m0_) do {                                                           \
    __builtin_amdgcn_s_setprio(1);                                               \
    _Pragma("unroll") for (int ni = 0; ni < 4; ++ni) {                           \
      MFMA16(acc[(m0_) + 0][ni], bfr[ni], afr[(m0_) + 0]);                       \
      MFMA16(acc[(m0_) + 1][ni], bfr[ni], afr[(m0_) + 1]);                       \
    }                                                                            \
    __builtin_amdgcn_s_setprio(0); } while (0)

  // ---- Prologue: stage tiles 0,1 (4 gl_lds each); drain tile0, tile1 in flight
  STAGE_A(0); STAGE_B(0);
  STAGE_A(1); STAGE_B(1);
  VMCNT4;
  BAR;

  for (int kt = 0; kt < NT; ++kt) {
    const int b = kt & 1;
    const bool more = (kt + 2 < NT);
    // ph1: all fragment reads of buf b (consumes sA[b], sB[b] entirely)
    LDB(b); LDA(b);
    BAR; LGKM0;
    MMA2(0);
    BAR;
    // ph2: stage tile kt+2 into buf b (safe after ph1 barrier); MMA; drain tile kt+1
    if (more) { STAGE_A(kt + 2); STAGE_B(kt + 2); }
    MMA2(2);
    if (more) { VMCNT4; } else { VMCNT0; }
    BAR;
  }

  // ---- Epilogue: acc -> swizzled LDS C-tile (128x128 f16 = 32KB, bias fused) -> coalesced stores
  // m = bm0 + wr*64 + mi*16 + rl ; n = bn0 + wc*64 + ni*16 + 4*kg + v
  {
    const int eRow0 = wr * 64 + rl;
    const int nq0   = wc * 64 + 4 * kg;
#pragma unroll
    for (int ni = 0; ni < 4; ++ni) {
      const int nloc = nq0 + ni * 16;
      const float4 b4 = *(const float4*)&bias_all[bn0 + nloc];
#pragma unroll
      for (int mi = 0; mi < 4; ++mi) {
        const int e = eRow0 + mi * 16;
        f16x4 h;
        h[0] = (f16)(acc[mi][ni][0] + b4.x);
        h[1] = (f16)(acc[mi][ni][1] + b4.y);
        h[2] = (f16)(acc[mi][ni][2] + b4.z);
        h[3] = (f16)(acc[mi][ni][3] + b4.w);
        *(f16x4*)&lds[e * 128 + (nloc ^ ((e & 7) << 3))] = h;
      }
    }
    LGKM0; BAR;
    const int rrow = t >> 4;       // 0..15
    const int rchk = t & 15;       // 0..15, 8 f16 each (row = 256B, wave covers 4 rows)
#pragma unroll
    for (int p = 0; p < 8; ++p) {
      const int row = p * 16 + rrow;
      f16x8 vdat = *(const f16x8*)&lds[row * 128 + ((rchk * 8) ^ ((row & 7) << 3))];
      *(f16x8*)&C[(size_t)(bm0 + row) * NCOLS + bn0 + rchk * 8] = vdat;
    }
  }
}

// ---------------- Kernel 3: gather + 4-way per-feature softmax + weighted sum ----------------
// XCD-chunked block swizzle: 3136 blocks = 8 * 392; each XCD gets 392 consecutive blocks.
__global__ __launch_bounds__(256) void attend(
    const f16* __restrict__ qkv,
    const int* __restrict__ img_ids, const float* __restrict__ eps,
    const float* __restrict__ avgs, const float* __restrict__ stds,
    float* __restrict__ out) {
  const int lane = threadIdx.x & 63;
  const int wid  = threadIdx.x >> 6;
  const int logical = (blockIdx.x & 7) * 392 + (blockIdx.x >> 3);
  const int gw = logical * 4 + wid;          // (b*196 + s)
  const int b = gw / NP;
  const int s = gw - b * NP;

  const int img = img_ids[b];
  const float ex = eps[(b * 2 + 0) * NP + s];
  const float ey = eps[(b * 2 + 1) * NP + s];
  const float mux = avgs[(img * 2 + 0) * NP + s];
  const float muy = avgs[(img * 2 + 1) * NP + s];
  const float sdx = stds[(img * 2 + 0) * NP + s];
  const float sdy = stds[(img * 2 + 1) * NP + s];

  const float kx = fmaf(sdx, ex, mux);
  const float ky = fmaf(sdy, ey, muy);
  const float kx1 = ceilf(kx), kx2 = floorf(kx);
  const float ky1 = ceilf(ky), ky2 = floorf(ky);

  int idx[4];
  idx[0] = (int)fminf(fmaxf(GRIDF * ky1 + kx1, 0.0f), 195.0f);
  idx[1] = (int)fminf(fmaxf(GRIDF * ky1 + kx2, 0.0f), 195.0f);
  idx[2] = (int)fminf(fmaxf(GRIDF * ky2 + kx1, 0.0f), 195.0f);
  idx[3] = (int)fminf(fmaxf(GRIDF * ky2 + kx2, 0.0f), 195.0f);

  const f16* qrow = qkv + (size_t)gw * NCOLS;
  const f16* base = qkv + (size_t)(b * NP) * NCOLS;
  const f16* k0p = base + (size_t)idx[0] * NCOLS + DIM;
  const f16* k1p = base + (size_t)idx[1] * NCOLS + DIM;
  const f16* k2p = base + (size_t)idx[2] * NCOLS + DIM;
  const f16* k3p = base + (size_t)idx[3] * NCOLS + DIM;
  const f16* v0p = k0p + DIM;
  const f16* v1p = k1p + DIM;
  const f16* v2p = k2p + DIM;
  const f16* v3p = k3p + DIM;
  float* orow = out + (size_t)gw * DIM;

#pragma unroll
  for (int seg = 0; seg < 3; ++seg) {
    const int e0 = seg * 256 + lane * 4;
    f16x4 qv  = *(const f16x4*)(qrow + e0);
    f16x4 kv0 = *(const f16x4*)(k0p + e0);
    f16x4 kv1 = *(const f16x4*)(k1p + e0);
    f16x4 kv2 = *(const f16x4*)(k2p + e0);
    f16x4 kv3 = *(const f16x4*)(k3p + e0);
    f16x4 vv0 = *(const f16x4*)(v0p + e0);
    f16x4 vv1 = *(const f16x4*)(v1p + e0);
    f16x4 vv2 = *(const f16x4*)(v2p + e0);
    f16x4 vv3 = *(const f16x4*)(v3p + e0);
    float4 o;
    float* op = &o.x;
#pragma unroll
    for (int c = 0; c < 4; ++c) {
      const float q = (float)qv[c];
      const float s0 = q * (float)kv0[c];
      const float s1 = q * (float)kv1[c];
      const float s2 = q * (float)kv2[c];
      const float s3 = q * (float)kv3[c];
      const float mx = fmaxf(fmaxf(s0, s1), fmaxf(s2, s3));
      const float w0 = __expf(s0 - mx);
      const float w1 = __expf(s1 - mx);
      const float w2 = __expf(s2 - mx);
      const float w3 = __expf(s3 - mx);
      const float den = w0 + w1 + w2 + w3;
      const float num = w0 * (float)vv0[c] + w1 * (float)vv1[c] +
                        w2 * (float)vv2[c] + w3 * (float)vv3[c];
      op[c] = num / den;
    }
    *(float4*)(orow + e0) = o;
  }
}

// ---------------- Launch ----------------
extern "C" void kernel_launch(void* const* d_in, const int* in_sizes, int n_in,
                              void* d_out, int out_size, void* d_ws, size_t ws_size,
                              hipStream_t stream) {
  const float* x       = (const float*)d_in[0];
  const int*   img_ids = (const int*)d_in[2];
  const float* eps     = (const float*)d_in[3];
  const float* Wq      = (const float*)d_in[4];
  const float* bq      = (const float*)d_in[5];
  const float* Wk      = (const float*)d_in[6];
  const float* bk      = (const float*)d_in[7];
  const float* Wv      = (const float*)d_in[8];
  const float* bv      = (const float*)d_in[9];
  const float* avgs    = (const float*)d_in[10];
  const float* stds    = (const float*)d_in[11];
  float* out = (float*)d_out;

  char* ws = (char*)d_ws;
  const size_t XH_BYTES = (size_t)MROWS * DIM * 2;   // 19,267,584
  const size_t WH_BYTES = (size_t)NCOLS * DIM * 2;   //  3,538,944
  const size_t BI_BYTES = (size_t)NCOLS * 4;         //      9,216
  f16*   x_h      = (f16*)ws;
  f16*   W_h      = (f16*)(ws + XH_BYTES);
  float* bias_all = (float*)(ws + XH_BYTES + WH_BYTES);
  f16*   qkv      = (f16*)(ws + XH_BYTES + WH_BYTES + BI_BYTES);

  {
    int grid = (NCVTA + 255) / 256;
    convert_inputs<<<grid, 256, 0, stream>>>(x, Wq, Wk, Wv, bq, bk, bv, x_h, W_h, bias_all);
  }
  {
    gemm_qkv<<<1764, 256, 0, stream>>>(x_h, W_h, bias_all, qkv);
  }
  {
    int grid = MROWS / 4;
    attend<<<grid, 256, 0, stream>>>(qkv, img_ids, eps, avgs, stds, out);
  }
}

// Round 9
// 84.506 us; speedup vs baseline: 1.1100x; 1.1100x over previous
//
#include <hip/hip_runtime.h>
#include <hip/hip_bf16.h>

typedef _Float16 f16;
typedef f16 f16x4 __attribute__((ext_vector_type(4)));
typedef f16 f16x8 __attribute__((ext_vector_type(8)));
typedef float f32x4 __attribute__((ext_vector_type(4)));

#define DIM   768
#define NP    196
#define BATCH 64
#define MROWS (BATCH * NP)        // 12544
#define NCOLS (3 * DIM)           // 2304
#define GRIDF 14.0f

// ---------------- Kernel 1: f32 -> f16 conversion of x and [Wq;Wk;Wv] + bias array ----------------
#define NX4   (MROWS * DIM / 4)   // 2,408,448
#define NW4   (DIM * DIM / 4)     // 147,456 per W
#define NB4   (NCOLS / 4)         // 576
#define NCVTA (NX4 + 3 * NW4 + NB4)

__global__ __launch_bounds__(256) void convert_inputs(
    const float* __restrict__ x,
    const float* __restrict__ Wq, const float* __restrict__ Wk, const float* __restrict__ Wv,
    const float* __restrict__ bq, const float* __restrict__ bk, const float* __restrict__ bv,
    f16* __restrict__ x_h, f16* __restrict__ W_h, float* __restrict__ bias_all) {
  int i = blockIdx.x * 256 + threadIdx.x;
  if (i >= NCVTA) return;
  if (i < NX4 + 3 * NW4) {
    const float* src;
    f16* dst;
    int j;
    if (i < NX4) { src = x; dst = x_h; j = i; }
    else {
      j = i - NX4;
      if (j < NW4)          { src = Wq; dst = W_h; }
      else if (j < 2 * NW4) { src = Wk; dst = W_h + DIM * DIM;     j -= NW4; }
      else                  { src = Wv; dst = W_h + 2 * DIM * DIM; j -= 2 * NW4; }
    }
    float4 v = ((const float4*)src)[j];
    f16x4 h;
    h[0] = (f16)v.x; h[1] = (f16)v.y; h[2] = (f16)v.z; h[3] = (f16)v.w;
    ((f16x4*)dst)[j] = h;
  } else {
    int j = i - (NX4 + 3 * NW4);   // 0..575
    float4 v = (j < 192) ? ((const float4*)bq)[j]
             : (j < 384) ? ((const float4*)bk)[j - 192]
                         : ((const float4*)bv)[j - 384];
    ((float4*)bias_all)[j] = v;
  }
}

// ---------------- Kernel 2: qkv = x_h @ W_h^T + bias (128x128, BK=64, 2 blocks/CU) ----------------
// A: (12544 x 768) f16 rm. W: (2304 x 768) f16 rm (B^T). BM=BN=128, BK=64,
// 4 waves (2M x 2N), wave tile 64x64 (acc = 64 regs). LDS 64 KB double-buffered ->
// 2 co-resident blocks/CU (launch_bounds(256,2)): cross-block TLP hides staging latency,
// and the 1764-block grid removes r7's 2-round quantization (441 @ 1/CU).
// Swizzle = r7's proven BK=64 slot XOR (bank-conflict-free on ds_read_b128, rule #21:
// pre-swizzled global source + linear LDS dest + swizzled ds_read).
// Schedule per K-tile (race-free, r8 structure):
//   ph1: all 16 fragment ds_reads (tile fully consumed); BAR; LGKM0; 16 MFMA (kh=0); BAR
//        (2nd BAR proves every wave's reads completed -> staging may overwrite)
//   ph2: stage tile kt+2 (8 gl_lds) into freed buf; 16 MFMA (kh=1); vmcnt(8) drains
//        tile kt+1 (8 in flight from kt+2 stay); BAR
#define BM 128
#define BN 128
#define BK 64
#define NT (DIM / BK)   // 12

__device__ __forceinline__ void gl_lds16(const f16* g, f16* l) {
  __builtin_amdgcn_global_load_lds(
      (const __attribute__((address_space(1))) void*)g,
      (__attribute__((address_space(3))) void*)l, 16, 0, 0);
}

#define MFMA16(acc_, av, bv) acc_ = __builtin_amdgcn_mfma_f32_16x16x32_f16(av, bv, acc_, 0, 0, 0)
#define BAR    __builtin_amdgcn_s_barrier()
#define LGKM0  asm volatile("s_waitcnt lgkmcnt(0)" ::: "memory")
#define VMCNT8 asm volatile("s_waitcnt vmcnt(8)" ::: "memory")
#define VMCNT0 asm volatile("s_waitcnt vmcnt(0)" ::: "memory")

#define sAoff(buf) ((buf) * (BM * BK))
#define sBoff(buf) (2 * BM * BK + (buf) * (BN * BK))

__global__ __launch_bounds__(256, 2) void gemm_qkv(
    const f16* __restrict__ A, const f16* __restrict__ W,
    const float* __restrict__ bias_all, f16* __restrict__ C) {
  __shared__ __align__(16) f16 lds[4 * BM * BK];   // 65536 B

  const int t    = threadIdx.x;
  const int lane = t & 63;
  const int wid  = t >> 6;
  const int wr   = wid >> 1;       // 0..1 (M)
  const int wc   = wid & 1;        // 0..1 (N)

  // Bijective XCD swizzle (m204) over 1764 blocks; logical: n fastest (18 N-blocks)
  const int nwg = 98 * 18, qq = nwg / 8, rr = nwg % 8;   // q=220, r=4
  const int xcd = blockIdx.x & 7, seq = blockIdx.x >> 3;
  const int logical = (xcd < rr ? xcd * (qq + 1) : rr * (qq + 1) + (xcd - rr) * qq) + seq;
  const int bm0 = (logical / 18) * BM;
  const int bn0 = (logical % 18) * BN;

  // Staging: thread covers (row = t>>3 in 0..31, slot = t&7); 4 chunks of 32 rows.
  // Source column pre-swizzled (slot ^ row&7); LDS dest linear. (row+32k)&7 == row&7.
  const int srow  = t >> 3;                    // 0..31
  const int sslot = t & 7;
  const int gcol  = 8 * (sslot ^ (srow & 7));  // swizzled source column (f16)
  const int lds_off = srow * BK + sslot * 8;   // linear dest (f16)
  const f16* gAr = A + (size_t)(bm0 + srow) * DIM + gcol;
  const f16* gBr = W + (size_t)(bn0 + srow) * DIM + gcol;

#define STAGE_A(kt) do {                                             \
    const f16* _g = gAr + (kt) * BK;                                 \
    f16* _l = &lds[sAoff((kt) & 1) + lds_off];                       \
    gl_lds16(_g,                       _l);                          \
    gl_lds16(_g + (size_t)32  * DIM,   _l + 32  * BK);               \
    gl_lds16(_g + (size_t)64  * DIM,   _l + 64  * BK);               \
    gl_lds16(_g + (size_t)96  * DIM,   _l + 96  * BK);               \
  } while (0)

#define STAGE_B(kt) do {                                             \
    const f16* _g = gBr + (kt) * BK;                                 \
    f16* _l = &lds[sBoff((kt) & 1) + lds_off];                       \
    gl_lds16(_g,                       _l);                          \
    gl_lds16(_g + (size_t)32  * DIM,   _l + 32  * BK);               \
    gl_lds16(_g + (size_t)64  * DIM,   _l + 64  * BK);               \
    gl_lds16(_g + (size_t)96  * DIM,   _l + 96  * BK);               \
  } while (0)

  // Fragment-read coords (r7 geometry): slot = ((kh*4 + kg) ^ (lane&7)) * 8
  const int rl = lane & 15;
  const int kg = lane >> 4;        // 0..3
  const int s7 = lane & 7;
  const int slot0 = ((0 * 4 + kg) ^ s7) * 8;   // kh=0 swizzled slot (f16)
  const int slot1 = ((1 * 4 + kg) ^ s7) * 8;   // kh=1
  const int aBase = (wr * 64 + rl) * BK;
  const int bBase = (wc * 64 + rl) * BK;

  f32x4 acc[4][4] = {};
  f16x8 afr[4][2], bfr[4][2];

#define LDAB(buf) do {                                                                  \
    _Pragma("unroll") for (int ni = 0; ni < 4; ++ni) {                                  \
      bfr[ni][0] = *(const f16x8*)&lds[sBoff(buf) + bBase + ni * 16 * BK + slot0];      \
      bfr[ni][1] = *(const f16x8*)&lds[sBoff(buf) + bBase + ni * 16 * BK + slot1];      \
    }                                                                                   \
    _Pragma("unroll") for (int mi = 0; mi < 4; ++mi) {                                  \
      afr[mi][0] = *(const f16x8*)&lds[sAoff(buf) + aBase + mi * 16 * BK + slot0];      \
      afr[mi][1] = *(const f16x8*)&lds[sAoff(buf) + aBase + mi * 16 * BK + slot1];      \
    } } while (0)

  // SWAPPED operand order: mfma(bfr, afr) -> m = lane&15 (A row), n = 4*kg + reg (B row)
#define MMA_KH(kh) do {                                                          \
    __builtin_amdgcn_s_setprio(1);                                               \
    _Pragma("unroll") for (int ni = 0; ni < 4; ++ni)                             \
      _Pragma("unroll") for (int mi = 0; mi < 4; ++mi)                           \
        MFMA16(acc[mi][ni], bfr[ni][kh], afr[mi][kh]);                           \
    __builtin_amdgcn_s_setprio(0); } while (0)

  // ---- Prologue: stage tiles 0,1 (8 gl_lds each); drain tile0, tile1 in flight
  STAGE_A(0); STAGE_B(0);
  STAGE_A(1); STAGE_B(1);
  VMCNT8;
  BAR;

  for (int kt = 0; kt < NT; ++kt) {
    const int b = kt & 1;
    const bool more = (kt + 2 < NT);
    // ph1: all fragment reads of buf b; after 2nd BAR every wave's reads are complete
    LDAB(b);
    BAR; LGKM0;
    MMA_KH(0);
    BAR;
    // ph2: stage tile kt+2 into buf b (now provably consumed); MFMA kh=1; drain kt+1
    if (more) { STAGE_A(kt + 2); STAGE_B(kt + 2); }
    MMA_KH(1);
    if (more) { VMCNT8; } else { VMCNT0; }
    BAR;
  }

  // ---- Epilogue: acc -> swizzled LDS C-tile (128x128 f16 = 32KB, bias fused) -> coalesced stores
  // m = bm0 + wr*64 + mi*16 + rl ; n = bn0 + wc*64 + ni*16 + 4*kg + v
  {
    const int eRow0 = wr * 64 + rl;
    const int nq0   = wc * 64 + 4 * kg;
#pragma unroll
    for (int ni = 0; ni < 4; ++ni) {
      const int nloc = nq0 + ni * 16;
      const float4 b4 = *(const float4*)&bias_all[bn0 + nloc];
#pragma unroll
      for (int mi = 0; mi < 4; ++mi) {
        const int e = eRow0 + mi * 16;
        f16x4 h;
        h[0] = (f16)(acc[mi][ni][0] + b4.x);
        h[1] = (f16)(acc[mi][ni][1] + b4.y);
        h[2] = (f16)(acc[mi][ni][2] + b4.z);
        h[3] = (f16)(acc[mi][ni][3] + b4.w);
        *(f16x4*)&lds[e * 128 + (nloc ^ ((e & 7) << 3))] = h;
      }
    }
    LGKM0; BAR;
    const int rrow = t >> 4;       // 0..15
    const int rchk = t & 15;       // 0..15, 8 f16 each
#pragma unroll
    for (int p = 0; p < 8; ++p) {
      const int row = p * 16 + rrow;
      f16x8 vdat = *(const f16x8*)&lds[row * 128 + ((rchk * 8) ^ ((row & 7) << 3))];
      *(f16x8*)&C[(size_t)(bm0 + row) * NCOLS + bn0 + rchk * 8] = vdat;
    }
  }
}

// ---------------- Kernel 3: gather + 4-way per-feature softmax + weighted sum ----------------
// XCD-chunked block swizzle: 3136 blocks = 8 * 392; each XCD gets 392 consecutive blocks.
__global__ __launch_bounds__(256) void attend(
    const f16* __restrict__ qkv,
    const int* __restrict__ img_ids, const float* __restrict__ eps,
    const float* __restrict__ avgs, const float* __restrict__ stds,
    float* __restrict__ out) {
  const int lane = threadIdx.x & 63;
  const int wid  = threadIdx.x >> 6;
  const int logical = (blockIdx.x & 7) * 392 + (blockIdx.x >> 3);
  const int gw = logical * 4 + wid;          // (b*196 + s)
  const int b = gw / NP;
  const int s = gw - b * NP;

  const int img = img_ids[b];
  const float ex = eps[(b * 2 + 0) * NP + s];
  const float ey = eps[(b * 2 + 1) * NP + s];
  const float mux = avgs[(img * 2 + 0) * NP + s];
  const float muy = avgs[(img * 2 + 1) * NP + s];
  const float sdx = stds[(img * 2 + 0) * NP + s];
  const float sdy = stds[(img * 2 + 1) * NP + s];

  const float kx = fmaf(sdx, ex, mux);
  const float ky = fmaf(sdy, ey, muy);
  const float kx1 = ceilf(kx), kx2 = floorf(kx);
  const float ky1 = ceilf(ky), ky2 = floorf(ky);

  int idx[4];
  idx[0] = (int)fminf(fmaxf(GRIDF * ky1 + kx1, 0.0f), 195.0f);
  idx[1] = (int)fminf(fmaxf(GRIDF * ky1 + kx2, 0.0f), 195.0f);
  idx[2] = (int)fminf(fmaxf(GRIDF * ky2 + kx1, 0.0f), 195.0f);
  idx[3] = (int)fminf(fmaxf(GRIDF * ky2 + kx2, 0.0f), 195.0f);

  const f16* qrow = qkv + (size_t)gw * NCOLS;
  const f16* base = qkv + (size_t)(b * NP) * NCOLS;
  const f16* k0p = base + (size_t)idx[0] * NCOLS + DIM;
  const f16* k1p = base + (size_t)idx[1] * NCOLS + DIM;
  const f16* k2p = base + (size_t)idx[2] * NCOLS + DIM;
  const f16* k3p = base + (size_t)idx[3] * NCOLS + DIM;
  const f16* v0p = k0p + DIM;
  const f16* v1p = k1p + DIM;
  const f16* v2p = k2p + DIM;
  const f16* v3p = k3p + DIM;
  float* orow = out + (size_t)gw * DIM;

#pragma unroll
  for (int seg = 0; seg < 3; ++seg) {
    const int e0 = seg * 256 + lane * 4;
    f16x4 qv  = *(const f16x4*)(qrow + e0);
    f16x4 kv0 = *(const f16x4*)(k0p + e0);
    f16x4 kv1 = *(const f16x4*)(k1p + e0);
    f16x4 kv2 = *(const f16x4*)(k2p + e0);
    f16x4 kv3 = *(const f16x4*)(k3p + e0);
    f16x4 vv0 = *(const f16x4*)(v0p + e0);
    f16x4 vv1 = *(const f16x4*)(v1p + e0);
    f16x4 vv2 = *(const f16x4*)(v2p + e0);
    f16x4 vv3 = *(const f16x4*)(v3p + e0);
    float4 o;
    float* op = &o.x;
#pragma unroll
    for (int c = 0; c < 4; ++c) {
      const float q = (float)qv[c];
      const float s0 = q * (float)kv0[c];
      const float s1 = q * (float)kv1[c];
      const float s2 = q * (float)kv2[c];
      const float s3 = q * (float)kv3[c];
      const float mx = fmaxf(fmaxf(s0, s1), fmaxf(s2, s3));
      const float w0 = __expf(s0 - mx);
      const float w1 = __expf(s1 - mx);
      const float w2 = __expf(s2 - mx);
      const float w3 = __expf(s3 - mx);
      const float den = w0 + w1 + w2 + w3;
      const float num = w0 * (float)vv0[c] + w1 * (float)vv1[c] +
                        w2 * (float)vv2[c] + w3 * (float)vv3[c];
      op[c] = num / den;
    }
    *(float4*)(orow + e0) = o;
  }
}

// ---------------- Launch ----------------
extern "C" void kernel_launch(void* const* d_in, const int* in_sizes, int n_in,
                              void* d_out, int out_size, void* d_ws, size_t ws_size,
                              hipStream_t stream) {
  const float* x       = (const float*)d_in[0];
  const int*   img_ids = (const int*)d_in[2];
  const float* eps     = (const float*)d_in[3];
  const float* Wq      = (const float*)d_in[4];
  const float* bq      = (const float*)d_in[5];
  const float* Wk      = (const float*)d_in[6];
  const float* bk      = (const float*)d_in[7];
  const float* Wv      = (const float*)d_in[8];
  const float* bv      = (const float*)d_in[9];
  const float* avgs    = (const float*)d_in[10];
  const float* stds    = (const float*)d_in[11];
  float* out = (float*)d_out;

  char* ws = (char*)d_ws;
  const size_t XH_BYTES = (size_t)MROWS * DIM * 2;   // 19,267,584
  const size_t WH_BYTES = (size_t)NCOLS * DIM * 2;   //  3,538,944
  const size_t BI_BYTES = (size_t)NCOLS * 4;         //      9,216
  f16*   x_h      = (f16*)ws;
  f16*   W_h      = (f16*)(ws + XH_BYTES);
  float* bias_all = (float*)(ws + XH_BYTES + WH_BYTES);
  f16*   qkv      = (f16*)(ws + XH_BYTES + WH_BYTES + BI_BYTES);

  {
    int grid = (NCVTA + 255) / 256;
    convert_inputs<<<grid, 256, 0, stream>>>(x, Wq, Wk, Wv, bq, bk, bv, x_h, W_h, bias_all);
  }
  {
    gemm_qkv<<<1764, 256, 0, stream>>>(x_h, W_h, bias_all, qkv);
  }
  {
    int grid = MROWS / 4;
    attend<<<grid, 256, 0, stream>>>(qkv, img_ids, eps, avgs, stds, out);
  }
}

// Round 10
// 83.444 us; speedup vs baseline: 1.1241x; 1.0127x over previous
//
#include <hip/hip_runtime.h>
#include <hip/hip_bf16.h>

typedef _Float16 f16;
typedef f16 f16x4 __attribute__((ext_vector_type(4)));
typedef f16 f16x8 __attribute__((ext_vector_type(8)));
typedef float f32x4 __attribute__((ext_vector_type(4)));

#define DIM   768
#define NP    196
#define BATCH 64
#define MROWS (BATCH * NP)        // 12544
#define NCOLS (3 * DIM)           // 2304
#define GRIDF 14.0f

// ---------------- Kernel 1: f32 -> f16 conversion of x and [Wq;Wk;Wv] + bias array ----------------
#define NX4   (MROWS * DIM / 4)   // 2,408,448
#define NW4   (DIM * DIM / 4)     // 147,456 per W
#define NB4   (NCOLS / 4)         // 576
#define NCVTA (NX4 + 3 * NW4 + NB4)

__global__ __launch_bounds__(256) void convert_inputs(
    const float* __restrict__ x,
    const float* __restrict__ Wq, const float* __restrict__ Wk, const float* __restrict__ Wv,
    const float* __restrict__ bq, const float* __restrict__ bk, const float* __restrict__ bv,
    f16* __restrict__ x_h, f16* __restrict__ W_h, float* __restrict__ bias_all) {
  int i = blockIdx.x * 256 + threadIdx.x;
  if (i >= NCVTA) return;
  if (i < NX4 + 3 * NW4) {
    const float* src;
    f16* dst;
    int j;
    if (i < NX4) { src = x; dst = x_h; j = i; }
    else {
      j = i - NX4;
      if (j < NW4)          { src = Wq; dst = W_h; }
      else if (j < 2 * NW4) { src = Wk; dst = W_h + DIM * DIM;     j -= NW4; }
      else                  { src = Wv; dst = W_h + 2 * DIM * DIM; j -= 2 * NW4; }
    }
    float4 v = ((const float4*)src)[j];
    f16x4 h;
    h[0] = (f16)v.x; h[1] = (f16)v.y; h[2] = (f16)v.z; h[3] = (f16)v.w;
    ((f16x4*)dst)[j] = h;
  } else {
    int j = i - (NX4 + 3 * NW4);   // 0..575
    float4 v = (j < 192) ? ((const float4*)bq)[j]
             : (j < 384) ? ((const float4*)bk)[j - 192]
                         : ((const float4*)bv)[j - 384];
    ((float4*)bias_all)[j] = v;
  }
}

// ---------------- Kernel 2: qkv = x_h @ W_h^T + bias (128x128, BK=64, 2 blocks/CU) ----------------
// r9 structure with counted-lgkm overlap (T4 on the LDS side) + barrier elision:
// per K-tile: {16 ds_reads, kh0-slot first} ; lgkmcnt(8) ; MMA(kh0) [kh1 reads drain under it] ;
//             lgkmcnt(0) ; BAR [staging-safety: all waves' reads complete] ;
//             stage kt+2 (8 gl_lds) ; MMA(kh1) ; vmcnt(8) [drains tile kt+1] ; BAR.
// 2 barriers/tile (was 3), half the LDS drain hidden under MFMA.
#define BM 128
#define BN 128
#define BK 64
#define NT (DIM / BK)   // 12

__device__ __forceinline__ void gl_lds16(const f16* g, f16* l) {
  __builtin_amdgcn_global_load_lds(
      (const __attribute__((address_space(1))) void*)g,
      (__attribute__((address_space(3))) void*)l, 16, 0, 0);
}

#define MFMA16(acc_, av, bv) acc_ = __builtin_amdgcn_mfma_f32_16x16x32_f16(av, bv, acc_, 0, 0, 0)
#define BAR    __builtin_amdgcn_s_barrier()
#define LGKM8  asm volatile("s_waitcnt lgkmcnt(8)" ::: "memory")
#define LGKM0  asm volatile("s_waitcnt lgkmcnt(0)" ::: "memory")
#define VMCNT8 asm volatile("s_waitcnt vmcnt(8)" ::: "memory")
#define VMCNT0 asm volatile("s_waitcnt vmcnt(0)" ::: "memory")

#define sAoff(buf) ((buf) * (BM * BK))
#define sBoff(buf) (2 * BM * BK + (buf) * (BN * BK))

__global__ __launch_bounds__(256, 2) void gemm_qkv(
    const f16* __restrict__ A, const f16* __restrict__ W,
    const float* __restrict__ bias_all, f16* __restrict__ C) {
  __shared__ __align__(16) f16 lds[4 * BM * BK];   // 65536 B

  const int t    = threadIdx.x;
  const int lane = t & 63;
  const int wid  = t >> 6;
  const int wr   = wid >> 1;       // 0..1 (M)
  const int wc   = wid & 1;        // 0..1 (N)

  // Bijective XCD swizzle (m204) over 1764 blocks; logical: n fastest (18 N-blocks)
  const int nwg = 98 * 18, qq = nwg / 8, rr = nwg % 8;   // q=220, r=4
  const int xcd = blockIdx.x & 7, seq = blockIdx.x >> 3;
  const int logical = (xcd < rr ? xcd * (qq + 1) : rr * (qq + 1) + (xcd - rr) * qq) + seq;
  const int bm0 = (logical / 18) * BM;
  const int bn0 = (logical % 18) * BN;

  // Staging: thread covers (row = t>>3 in 0..31, slot = t&7); 4 chunks of 32 rows.
  // Source column pre-swizzled (slot ^ row&7); LDS dest linear. (row+32k)&7 == row&7.
  const int srow  = t >> 3;                    // 0..31
  const int sslot = t & 7;
  const int gcol  = 8 * (sslot ^ (srow & 7));  // swizzled source column (f16)
  const int lds_off = srow * BK + sslot * 8;   // linear dest (f16)
  const f16* gAr = A + (size_t)(bm0 + srow) * DIM + gcol;
  const f16* gBr = W + (size_t)(bn0 + srow) * DIM + gcol;

#define STAGE_A(kt) do {                                             \
    const f16* _g = gAr + (kt) * BK;                                 \
    f16* _l = &lds[sAoff((kt) & 1) + lds_off];                       \
    gl_lds16(_g,                       _l);                          \
    gl_lds16(_g + (size_t)32  * DIM,   _l + 32  * BK);               \
    gl_lds16(_g + (size_t)64  * DIM,   _l + 64  * BK);               \
    gl_lds16(_g + (size_t)96  * DIM,   _l + 96  * BK);               \
  } while (0)

#define STAGE_B(kt) do {                                             \
    const f16* _g = gBr + (kt) * BK;                                 \
    f16* _l = &lds[sBoff((kt) & 1) + lds_off];                       \
    gl_lds16(_g,                       _l);                          \
    gl_lds16(_g + (size_t)32  * DIM,   _l + 32  * BK);               \
    gl_lds16(_g + (size_t)64  * DIM,   _l + 64  * BK);               \
    gl_lds16(_g + (size_t)96  * DIM,   _l + 96  * BK);               \
  } while (0)

  // Fragment-read coords (r7 geometry): slot = ((kh*4 + kg) ^ (lane&7)) * 8
  const int rl = lane & 15;
  const int kg = lane >> 4;        // 0..3
  const int s7 = lane & 7;
  const int slot0 = ((0 * 4 + kg) ^ s7) * 8;   // kh=0 swizzled slot (f16)
  const int slot1 = ((1 * 4 + kg) ^ s7) * 8;   // kh=1
  const int aBase = (wr * 64 + rl) * BK;
  const int bBase = (wc * 64 + rl) * BK;

  f32x4 acc[4][4] = {};
  f16x8 afr[4][2], bfr[4][2];

  // kh0-slot reads FIRST (8), then kh1 (8) -> lgkmcnt(8) == "kh0 fragments resident"
#define LDAB_KH0(buf) do {                                                              \
    _Pragma("unroll") for (int ni = 0; ni < 4; ++ni)                                    \
      bfr[ni][0] = *(const f16x8*)&lds[sBoff(buf) + bBase + ni * 16 * BK + slot0];      \
    _Pragma("unroll") for (int mi = 0; mi < 4; ++mi)                                    \
      afr[mi][0] = *(const f16x8*)&lds[sAoff(buf) + aBase + mi * 16 * BK + slot0];      \
    } while (0)

#define LDAB_KH1(buf) do {                                                              \
    _Pragma("unroll") for (int ni = 0; ni < 4; ++ni)                                    \
      bfr[ni][1] = *(const f16x8*)&lds[sBoff(buf) + bBase + ni * 16 * BK + slot1];      \
    _Pragma("unroll") for (int mi = 0; mi < 4; ++mi)                                    \
      afr[mi][1] = *(const f16x8*)&lds[sAoff(buf) + aBase + mi * 16 * BK + slot1];      \
    } while (0)

  // SWAPPED operand order: mfma(bfr, afr) -> m = lane&15 (A row), n = 4*kg + reg (B row)
#define MMA_KH(kh) do {                                                          \
    __builtin_amdgcn_s_setprio(1);                                               \
    _Pragma("unroll") for (int ni = 0; ni < 4; ++ni)                             \
      _Pragma("unroll") for (int mi = 0; mi < 4; ++mi)                           \
        MFMA16(acc[mi][ni], bfr[ni][kh], afr[mi][kh]);                           \
    __builtin_amdgcn_s_setprio(0); } while (0)

  // ---- Prologue: stage tiles 0,1 (8 gl_lds each); drain tile0, tile1 in flight
  STAGE_A(0); STAGE_B(0);
  STAGE_A(1); STAGE_B(1);
  VMCNT8;
  BAR;

  for (int kt = 0; kt < NT; ++kt) {
    const int b = kt & 1;
    const bool more = (kt + 2 < NT);
    // issue all 16 fragment reads, kh0 first
    LDAB_KH0(b);
    LDAB_KH1(b);
    LGKM8;              // kh0 fragments resident; kh1 still draining
    MMA_KH(0);
    LGKM0; BAR;         // all waves' reads of buf b complete -> buf b reusable
    if (more) { STAGE_A(kt + 2); STAGE_B(kt + 2); }
    MMA_KH(1);
    if (more) { VMCNT8; } else { VMCNT0; }   // tile kt+1 landed (kt+2's 8 stay in flight)
    BAR;
  }

  // ---- Epilogue: acc -> swizzled LDS C-tile (128x128 f16 = 32KB, bias fused) -> coalesced stores
  // m = bm0 + wr*64 + mi*16 + rl ; n = bn0 + wc*64 + ni*16 + 4*kg + v
  {
    const int eRow0 = wr * 64 + rl;
    const int nq0   = wc * 64 + 4 * kg;
#pragma unroll
    for (int ni = 0; ni < 4; ++ni) {
      const int nloc = nq0 + ni * 16;
      const float4 b4 = *(const float4*)&bias_all[bn0 + nloc];
#pragma unroll
      for (int mi = 0; mi < 4; ++mi) {
        const int e = eRow0 + mi * 16;
        f16x4 h;
        h[0] = (f16)(acc[mi][ni][0] + b4.x);
        h[1] = (f16)(acc[mi][ni][1] + b4.y);
        h[2] = (f16)(acc[mi][ni][2] + b4.z);
        h[3] = (f16)(acc[mi][ni][3] + b4.w);
        *(f16x4*)&lds[e * 128 + (nloc ^ ((e & 7) << 3))] = h;
      }
    }
    LGKM0; BAR;
    const int rrow = t >> 4;       // 0..15
    const int rchk = t & 15;       // 0..15, 8 f16 each
#pragma unroll
    for (int p = 0; p < 8; ++p) {
      const int row = p * 16 + rrow;
      f16x8 vdat = *(const f16x8*)&lds[row * 128 + ((rchk * 8) ^ ((row & 7) << 3))];
      *(f16x8*)&C[(size_t)(bm0 + row) * NCOLS + bn0 + rchk * 8] = vdat;
    }
  }
}

// ---------------- Kernel 3: gather + 4-way per-feature softmax + weighted sum ----------------
// XCD-chunked block swizzle: 3136 blocks = 8 * 392; each XCD gets 392 consecutive blocks.
__global__ __launch_bounds__(256) void attend(
    const f16* __restrict__ qkv,
    const int* __restrict__ img_ids, const float* __restrict__ eps,
    const float* __restrict__ avgs, const float* __restrict__ stds,
    float* __restrict__ out) {
  const int lane = threadIdx.x & 63;
  const int wid  = threadIdx.x >> 6;
  const int logical = (blockIdx.x & 7) * 392 + (blockIdx.x >> 3);
  const int gw = logical * 4 + wid;          // (b*196 + s)
  const int b = gw / NP;
  const int s = gw - b * NP;

  const int img = img_ids[b];
  const float ex = eps[(b * 2 + 0) * NP + s];
  const float ey = eps[(b * 2 + 1) * NP + s];
  const float mux = avgs[(img * 2 + 0) * NP + s];
  const float muy = avgs[(img * 2 + 1) * NP + s];
  const float sdx = stds[(img * 2 + 0) * NP + s];
  const float sdy = stds[(img * 2 + 1) * NP + s];

  const float kx = fmaf(sdx, ex, mux);
  const float ky = fmaf(sdy, ey, muy);
  const float kx1 = ceilf(kx), kx2 = floorf(kx);
  const float ky1 = ceilf(ky), ky2 = floorf(ky);

  int idx[4];
  idx[0] = (int)fminf(fmaxf(GRIDF * ky1 + kx1, 0.0f), 195.0f);
  idx[1] = (int)fminf(fmaxf(GRIDF * ky1 + kx2, 0.0f), 195.0f);
  idx[2] = (int)fminf(fmaxf(GRIDF * ky2 + kx1, 0.0f), 195.0f);
  idx[3] = (int)fminf(fmaxf(GRIDF * ky2 + kx2, 0.0f), 195.0f);

  const f16* qrow = qkv + (size_t)gw * NCOLS;
  const f16* base = qkv + (size_t)(b * NP) * NCOLS;
  const f16* k0p = base + (size_t)idx[0] * NCOLS + DIM;
  const f16* k1p = base + (size_t)idx[1] * NCOLS + DIM;
  const f16* k2p = base + (size_t)idx[2] * NCOLS + DIM;
  const f16* k3p = base + (size_t)idx[3] * NCOLS + DIM;
  const f16* v0p = k0p + DIM;
  const f16* v1p = k1p + DIM;
  const f16* v2p = k2p + DIM;
  const f16* v3p = k3p + DIM;
  float* orow = out + (size_t)gw * DIM;

#pragma unroll
  for (int seg = 0; seg < 3; ++seg) {
    const int e0 = seg * 256 + lane * 4;
    f16x4 qv  = *(const f16x4*)(qrow + e0);
    f16x4 kv0 = *(const f16x4*)(k0p + e0);
    f16x4 kv1 = *(const f16x4*)(k1p + e0);
    f16x4 kv2 = *(const f16x4*)(k2p + e0);
    f16x4 kv3 = *(const f16x4*)(k3p + e0);
    f16x4 vv0 = *(const f16x4*)(v0p + e0);
    f16x4 vv1 = *(const f16x4*)(v1p + e0);
    f16x4 vv2 = *(const f16x4*)(v2p + e0);
    f16x4 vv3 = *(const f16x4*)(v3p + e0);
    float4 o;
    float* op = &o.x;
#pragma unroll
    for (int c = 0; c < 4; ++c) {
      const float q = (float)qv[c];
      const float s0 = q * (float)kv0[c];
      const float s1 = q * (float)kv1[c];
      const float s2 = q * (float)kv2[c];
      const float s3 = q * (float)kv3[c];
      const float mx = fmaxf(fmaxf(s0, s1), fmaxf(s2, s3));
      const float w0 = __expf(s0 - mx);
      const float w1 = __expf(s1 - mx);
      const float w2 = __expf(s2 - mx);
      const float w3 = __expf(s3 - mx);
      const float den = w0 + w1 + w2 + w3;
      const float num = w0 * (float)vv0[c] + w1 * (float)vv1[c] +
                        w2 * (float)vv2[c] + w3 * (float)vv3[c];
      op[c] = num / den;
    }
    *(float4*)(orow + e0) = o;
  }
}

// ---------------- Launch ----------------
extern "C" void kernel_launch(void* const* d_in, const int* in_sizes, int n_in,
                              void* d_out, int out_size, void* d_ws, size_t ws_size,
                              hipStream_t stream) {
  const float* x       = (const float*)d_in[0];
  const int*   img_ids = (const int*)d_in[2];
  const float* eps     = (const float*)d_in[3];
  const float* Wq      = (const float*)d_in[4];
  const float* bq      = (const float*)d_in[5];
  const float* Wk      = (const float*)d_in[6];
  const float* bk      = (const float*)d_in[7];
  const float* Wv      = (const float*)d_in[8];
  const float* bv      = (const float*)d_in[9];
  const float* avgs    = (const float*)d_in[10];
  const float* stds    = (const float*)d_in[11];
  float* out = (float*)d_out;

  char* ws = (char*)d_ws;
  const size_t XH_BYTES = (size_t)MROWS * DIM * 2;   // 19,267,584
  const size_t WH_BYTES = (size_t)NCOLS * DIM * 2;   //  3,538,944
  const size_t BI_BYTES = (size_t)NCOLS * 4;         //      9,216
  f16*   x_h      = (f16*)ws;
  f16*   W_h      = (f16*)(ws + XH_BYTES);
  float* bias_all = (float*)(ws + XH_BYTES + WH_BYTES);
  f16*   qkv      = (f16*)(ws + XH_BYTES + WH_BYTES + BI_BYTES);

  {
    int grid = (NCVTA + 255) / 256;
    convert_inputs<<<grid, 256, 0, stream>>>(x, Wq, Wk, Wv, bq, bk, bv, x_h, W_h, bias_all);
  }
  {
    gemm_qkv<<<1764, 256, 0, stream>>>(x_h, W_h, bias_all, qkv);
  }
  {
    int grid = MROWS / 4;
    attend<<<grid, 256, 0, stream>>>(qkv, img_ids, eps, avgs, stds, out);
  }
}